// Round 1
// baseline (160.784 us; speedup 1.0000x reference)
//
#include <hip/hip_runtime.h>
#include <math.h>

// Problem constants (fixed by setup_inputs)
#define B   16
#define L   512
#define H   768
#define HV4 192      // H/4 float4s per row
#define S1  32
#define S2  128
#define NS  8
#define M   4
#define CH  16       // L-chunk rows per partial block
#define NCHUNK 32    // L / CH

// ---------------------------------------------------------------------------
// K1: row_cls[i,h] = sum_j am[i,j]*(e1[i,j,h]+e2[i,j,h]) / sum_j am[i,j]
// One block per explanation row i (512 blocks), 192 threads (float4 per thread).
// Compact selected j-indices into LDS so the main loop is branch-free and
// deeply pipelined (8 float4 loads in flight per thread).
// ---------------------------------------------------------------------------
__global__ __launch_bounds__(192)
void k_row_cls(const float* __restrict__ e1, const float* __restrict__ e2,
               const int* __restrict__ am, float* __restrict__ row_cls) {
  const int i = blockIdx.x;
  const int t = threadIdx.x;
  __shared__ float mk[S2];
  __shared__ int   idxL[S2];
  __shared__ float mvL[S2];
  __shared__ int   cntS;
  __shared__ float msumS;
  if (t < S2) mk[t] = (float)am[i * S2 + t];
  __syncthreads();
  if (t == 0) {
    int c = 0; float s = 0.f;
    for (int j = 0; j < S2; ++j) {
      float m = mk[j]; s += m;
      if (m != 0.f) { idxL[c] = j; mvL[c] = m; ++c; }
    }
    cntS = c; msumS = s;
  }
  __syncthreads();
  const int cnt = cntS;
  const float4* p1 = (const float4*)e1 + (size_t)i * (S2 * HV4);
  const float4* p2 = (const float4*)e2 + (size_t)i * (S2 * HV4);
  float ax = 0.f, ay = 0.f, az = 0.f, aw = 0.f;
  int kk = 0;
  for (; kk + 3 < cnt; kk += 4) {
    int j0 = idxL[kk], j1 = idxL[kk + 1], j2 = idxL[kk + 2], j3 = idxL[kk + 3];
    float m0 = mvL[kk], m1 = mvL[kk + 1], m2 = mvL[kk + 2], m3 = mvL[kk + 3];
    float4 a0 = p1[j0 * HV4 + t], b0 = p2[j0 * HV4 + t];
    float4 a1 = p1[j1 * HV4 + t], b1 = p2[j1 * HV4 + t];
    float4 a2 = p1[j2 * HV4 + t], b2 = p2[j2 * HV4 + t];
    float4 a3 = p1[j3 * HV4 + t], b3 = p2[j3 * HV4 + t];
    ax += m0 * (a0.x + b0.x) + m1 * (a1.x + b1.x) + m2 * (a2.x + b2.x) + m3 * (a3.x + b3.x);
    ay += m0 * (a0.y + b0.y) + m1 * (a1.y + b1.y) + m2 * (a2.y + b2.y) + m3 * (a3.y + b3.y);
    az += m0 * (a0.z + b0.z) + m1 * (a1.z + b1.z) + m2 * (a2.z + b2.z) + m3 * (a3.z + b3.z);
    aw += m0 * (a0.w + b0.w) + m1 * (a1.w + b1.w) + m2 * (a2.w + b2.w) + m3 * (a3.w + b3.w);
  }
  for (; kk < cnt; ++kk) {
    int j = idxL[kk]; float m = mvL[kk];
    float4 a = p1[j * HV4 + t], b = p2[j * HV4 + t];
    ax += m * (a.x + b.x); ay += m * (a.y + b.y);
    az += m * (a.z + b.z); aw += m * (a.w + b.w);
  }
  float inv = 1.f / msumS;
  float4 o; o.x = ax * inv; o.y = ay * inv; o.z = az * inv; o.w = aw * inv;
  ((float4*)row_cls)[(size_t)i * HV4 + t] = o;
}

// ---------------------------------------------------------------------------
// K2: partial masked sums of (sent_h1+sent_h2) over 16-row L-chunks.
// Grid: B*NCHUNK = 512 blocks, 192 threads.
// ---------------------------------------------------------------------------
__global__ __launch_bounds__(192)
void k_sent_partial(const float* __restrict__ s1, const float* __restrict__ s2,
                    const int* __restrict__ iam, float* __restrict__ part,
                    float* __restrict__ cnt) {
  const int blk = blockIdx.x;
  const int b = blk >> 5, c = blk & 31;
  const int t = threadIdx.x;
  __shared__ float mk[CH];
  __shared__ int   idxL[CH];
  __shared__ float mvL[CH];
  __shared__ int   cntS;
  if (t < CH) mk[t] = (float)iam[b * L + c * CH + t];
  __syncthreads();
  if (t == 0) {
    int cc = 0; float s = 0.f;
    for (int l = 0; l < CH; ++l) {
      float m = mk[l]; s += m;
      if (m != 0.f) { idxL[cc] = l; mvL[cc] = m; ++cc; }
    }
    cntS = cc; cnt[blk] = s;
  }
  __syncthreads();
  const int cn = cntS;
  const float4* p1 = (const float4*)s1 + ((size_t)b * L + c * CH) * HV4;
  const float4* p2 = (const float4*)s2 + ((size_t)b * L + c * CH) * HV4;
  float ax = 0.f, ay = 0.f, az = 0.f, aw = 0.f;
  int kk = 0;
  for (; kk + 1 < cn; kk += 2) {
    int l0 = idxL[kk], l1 = idxL[kk + 1];
    float m0 = mvL[kk], m1 = mvL[kk + 1];
    float4 a0 = p1[l0 * HV4 + t], b0 = p2[l0 * HV4 + t];
    float4 a1 = p1[l1 * HV4 + t], b1 = p2[l1 * HV4 + t];
    ax += m0 * (a0.x + b0.x) + m1 * (a1.x + b1.x);
    ay += m0 * (a0.y + b0.y) + m1 * (a1.y + b1.y);
    az += m0 * (a0.z + b0.z) + m1 * (a1.z + b1.z);
    aw += m0 * (a0.w + b0.w) + m1 * (a1.w + b1.w);
  }
  for (; kk < cn; ++kk) {
    int l = idxL[kk]; float m = mvL[kk];
    float4 a = p1[l * HV4 + t], b = p2[l * HV4 + t];
    ax += m * (a.x + b.x); ay += m * (a.y + b.y);
    az += m * (a.z + b.z); aw += m * (a.w + b.w);
  }
  float4 o; o.x = ax; o.y = ay; o.z = az; o.w = aw;
  ((float4*)part)[(size_t)blk * HV4 + t] = o;
}

// ---------------------------------------------------------------------------
// K3: partial span sums of hidden_states (span is a contiguous interval).
// ---------------------------------------------------------------------------
__global__ __launch_bounds__(192)
void k_sel_partial(const float* __restrict__ hs, const int* __restrict__ st_,
                   const int* __restrict__ en_, float* __restrict__ part,
                   float* __restrict__ cnt) {
  const int blk = blockIdx.x;
  const int b = blk >> 5, c = blk & 31;
  const int t = threadIdx.x;
  const int st = st_[b], en = en_[b];
  int lo = st > c * CH ? st : c * CH;
  int hi = en < c * CH + CH ? en : c * CH + CH;
  const float4* p = (const float4*)hs + (size_t)b * L * HV4;
  float ax = 0.f, ay = 0.f, az = 0.f, aw = 0.f;
  int l = lo;
  for (; l + 1 < hi; l += 2) {
    float4 a0 = p[l * HV4 + t];
    float4 a1 = p[(l + 1) * HV4 + t];
    ax += a0.x + a1.x; ay += a0.y + a1.y; az += a0.z + a1.z; aw += a0.w + a1.w;
  }
  if (l < hi) {
    float4 a0 = p[l * HV4 + t];
    ax += a0.x; ay += a0.y; az += a0.z; aw += a0.w;
  }
  float4 o; o.x = ax; o.y = ay; o.z = az; o.w = aw;
  ((float4*)part)[(size_t)blk * HV4 + t] = o;
  if (t == 0) cnt[blk] = (float)(hi > lo ? hi - lo : 0);
}

// ---------------------------------------------------------------------------
// K4: combine partials -> sp[b,:], sel (layernormed with gamma_s/beta_s),
// and q[b,:] = sp[b,:] @ W_attn.  Grid: B blocks, 256 threads.
// ---------------------------------------------------------------------------
__global__ __launch_bounds__(256)
void k_finalize(const float* __restrict__ sp_part, const float* __restrict__ sp_cnt,
                const float* __restrict__ sel_part, const float* __restrict__ sel_cnt,
                const float* __restrict__ W_attn,
                const float* __restrict__ gamma_s, const float* __restrict__ beta_s,
                float* __restrict__ sp, float* __restrict__ sel_ln,
                float* __restrict__ q) {
  const int b = blockIdx.x, t = threadIdx.x;
  __shared__ float spL[H];
  __shared__ float red[256];
  __shared__ float mean_s, var_s;
  float csp = 0.f, csel = 0.f;
  for (int c = 0; c < NCHUNK; ++c) {
    csp += sp_cnt[b * NCHUNK + c];
    csel += sel_cnt[b * NCHUNK + c];
  }
  float spv[3], selv[3];
  #pragma unroll
  for (int k = 0; k < 3; ++k) {
    const int h = t + k * 256;
    float a = 0.f, s = 0.f;
    for (int c = 0; c < NCHUNK; ++c) {
      a += sp_part[((size_t)b * NCHUNK + c) * H + h];
      s += sel_part[((size_t)b * NCHUNK + c) * H + h];
    }
    spv[k] = a / csp;
    selv[k] = s / csel;
    spL[h] = spv[k];
    sp[(size_t)b * H + h] = spv[k];
  }
  // LayerNorm of selv over H
  red[t] = selv[0] + selv[1] + selv[2];
  __syncthreads();
  for (int s = 128; s > 0; s >>= 1) { if (t < s) red[t] += red[t + s]; __syncthreads(); }
  if (t == 0) mean_s = red[0] / (float)H;
  __syncthreads();
  const float mu = mean_s;
  float lv = 0.f;
  #pragma unroll
  for (int k = 0; k < 3; ++k) { float d = selv[k] - mu; lv += d * d; }
  red[t] = lv;
  __syncthreads();
  for (int s = 128; s > 0; s >>= 1) { if (t < s) red[t] += red[t + s]; __syncthreads(); }
  if (t == 0) var_s = red[0] / (float)H;
  __syncthreads();
  const float rstd = rsqrtf(var_s + 1e-12f);
  #pragma unroll
  for (int k = 0; k < 3; ++k) {
    const int h = t + k * 256;
    sel_ln[(size_t)b * H + h] = (selv[k] - mu) * rstd * gamma_s[h] + beta_s[h];
  }
  // q[b,h] = sum_d spL[d] * W_attn[d,h]  (coalesced over h)
  float a0 = 0.f, a1 = 0.f, a2 = 0.f;
  for (int d = 0; d < H; ++d) {
    const float s = spL[d];
    const float* wr = W_attn + (size_t)d * H;
    a0 += s * wr[t];
    a1 += s * wr[t + 256];
    a2 += s * wr[t + 512];
  }
  q[(size_t)b * H + t]       = a0;
  q[(size_t)b * H + t + 256] = a1;
  q[(size_t)b * H + t + 512] = a2;
}

// ---------------------------------------------------------------------------
// K5: sim -> ragged softmax -> pooled.  Grid: B*NS = 128 blocks, 256 threads.
// ---------------------------------------------------------------------------
__global__ __launch_bounds__(256)
void k_attn_pool(const float* __restrict__ row_cls, const float* __restrict__ q,
                 const int* __restrict__ extra_index, float* __restrict__ pooled) {
  const int blk = blockIdx.x;
  const int b = blk >> 3, n = blk & 7;
  const int t = threadIdx.x;
  const size_t base = ((size_t)b * S1 + n * M) * H;
  __shared__ float red[256];
  __shared__ float wgt[M];
  float qv[3];
  #pragma unroll
  for (int k = 0; k < 3; ++k) qv[k] = q[(size_t)b * H + t + k * 256];
  #pragma unroll
  for (int m = 0; m < M; ++m) {
    float p = 0.f;
    #pragma unroll
    for (int k = 0; k < 3; ++k) {
      const int h = t + k * 256;
      p += qv[k] * row_cls[base + (size_t)m * H + h];
    }
    red[t] = p;
    __syncthreads();
    for (int s = 128; s > 0; s >>= 1) { if (t < s) red[t] += red[t + s]; __syncthreads(); }
    if (t == 0) wgt[m] = red[0];
    __syncthreads();
  }
  if (t == 0) {
    const int vid = extra_index[b * NS + n];
    const float scale = 0.036084391824351615f;  // 1/sqrt(768)
    float x[M], mx = -1e30f;
    #pragma unroll
    for (int m = 0; m < M; ++m) {
      x[m] = (m < vid) ? wgt[m] * scale : -1e30f;
      mx = fmaxf(mx, x[m]);
    }
    float s = 0.f, e[M];
    #pragma unroll
    for (int m = 0; m < M; ++m) { e[m] = expf(x[m] - mx); s += e[m]; }
    #pragma unroll
    for (int m = 0; m < M; ++m) wgt[m] = e[m] / s;
  }
  __syncthreads();
  #pragma unroll
  for (int k = 0; k < 3; ++k) {
    const int h = t + k * 256;
    float acc = 0.f;
    #pragma unroll
    for (int m = 0; m < M; ++m) acc += wgt[m] * row_cls[base + (size_t)m * H + h];
    pooled[(size_t)blk * H + h] = acc;
  }
}

// ---------------------------------------------------------------------------
// K6: y[b,n,h] = pooled[b,n,:] . W_t[h,:] + b_t[h]
// Grid: B * 12 blocks (h-tile of 64), 256 threads, pooled rows staged in LDS.
// ---------------------------------------------------------------------------
__global__ __launch_bounds__(256)
void k_transform(const float* __restrict__ pooled, const float* __restrict__ W_t,
                 const float* __restrict__ b_t, float* __restrict__ y) {
  const int blk = blockIdx.x;
  const int b = blk / 12, hc = blk % 12;
  const int t = threadIdx.x;
  __shared__ float pL[NS * H];  // 24 KiB
  for (int idx = t; idx < NS * H; idx += 256)
    pL[idx] = pooled[(size_t)b * NS * H + idx];
  __syncthreads();
  #pragma unroll
  for (int rep = 0; rep < 2; ++rep) {
    const int idx = t + rep * 256;
    const int n = idx >> 6;
    const int h = hc * 64 + (idx & 63);
    const float* wr = W_t + (size_t)h * H;
    const float* pr = pL + n * H;
    float acc = 0.f;
    #pragma unroll 4
    for (int d = 0; d < H; ++d) acc += pr[d] * wr[d];
    y[((size_t)b * NS + n) * H + h] = acc + b_t[h];
  }
}

// ---------------------------------------------------------------------------
// K7: row LayerNorm (gamma_t/beta_t).  Grid: B*NS = 128 blocks, 256 threads.
// ---------------------------------------------------------------------------
__global__ __launch_bounds__(256)
void k_ln_rows(const float* __restrict__ y, const float* __restrict__ gamma,
               const float* __restrict__ beta, float* __restrict__ o) {
  const int r = blockIdx.x, t = threadIdx.x;
  __shared__ float red[256];
  __shared__ float mean_s, var_s;
  float v[3];
  #pragma unroll
  for (int k = 0; k < 3; ++k) v[k] = y[(size_t)r * H + t + k * 256];
  red[t] = v[0] + v[1] + v[2];
  __syncthreads();
  for (int s = 128; s > 0; s >>= 1) { if (t < s) red[t] += red[t + s]; __syncthreads(); }
  if (t == 0) mean_s = red[0] / (float)H;
  __syncthreads();
  const float mu = mean_s;
  float lv = 0.f;
  #pragma unroll
  for (int k = 0; k < 3; ++k) { float d = v[k] - mu; lv += d * d; }
  red[t] = lv;
  __syncthreads();
  for (int s = 128; s > 0; s >>= 1) { if (t < s) red[t] += red[t + s]; __syncthreads(); }
  if (t == 0) var_s = red[0] / (float)H;
  __syncthreads();
  const float rstd = rsqrtf(var_s + 1e-12f);
  #pragma unroll
  for (int k = 0; k < 3; ++k) {
    const int h = t + k * 256;
    o[(size_t)r * H + h] = (v[k] - mu) * rstd * gamma[h] + beta[h];
  }
}

// ---------------------------------------------------------------------------
// K8: cosine-similarity score over the NS axis.  Grid: B blocks, 256 threads.
// ---------------------------------------------------------------------------
__global__ __launch_bounds__(256)
void k_score(const float* __restrict__ cls_out, const float* __restrict__ sel_ln,
             float* __restrict__ out) {
  const int b = blockIdx.x, t = threadIdx.x;
  #pragma unroll
  for (int k = 0; k < 3; ++k) {
    const int h = t + k * 256;
    const float sl = sel_ln[(size_t)b * H + h];
    float S = 0.f, SS = 0.f;
    #pragma unroll
    for (int n = 0; n < NS; ++n) {
      const float v = cls_out[((size_t)b * NS + n) * H + h];
      S += v; SS += v * v;
    }
    const float n1 = 2.8284271247461903f * fabsf(sl);  // sqrt(8)*|sel|
    const float n2 = sqrtf(SS);
    out[(size_t)b * H + h] = sl * S / (fmaxf(n1, 1e-8f) * fmaxf(n2, 1e-8f));
  }
}

// ---------------------------------------------------------------------------
extern "C" void kernel_launch(void* const* d_in, const int* in_sizes, int n_in,
                              void* d_out, int out_size, void* d_ws, size_t ws_size,
                              hipStream_t stream) {
  const float* hidden_states = (const float*)d_in[0];
  const float* sent_h1       = (const float*)d_in[1];
  const float* sent_h2       = (const float*)d_in[2];
  const int*   attention_mask= (const int*)  d_in[3];
  const float* expl_h1       = (const float*)d_in[4];
  const float* expl_h2       = (const float*)d_in[5];
  const int*   extra_am      = (const int*)  d_in[6];
  const int*   extra_index   = (const int*)  d_in[7];
  const int*   extra_start   = (const int*)  d_in[8];
  const int*   extra_end     = (const int*)  d_in[9];
  const float* W_attn        = (const float*)d_in[10];
  const float* W_t           = (const float*)d_in[11];
  const float* b_t           = (const float*)d_in[12];
  const float* gamma_t       = (const float*)d_in[13];
  const float* beta_t        = (const float*)d_in[14];
  const float* gamma_s       = (const float*)d_in[15];
  const float* beta_s        = (const float*)d_in[16];
  float* out = (float*)d_out;

  float* ws = (float*)d_ws;
  float* row_cls  = ws;                       // 512*768
  float* sp_part  = row_cls + 512 * H;        // 512*768
  float* sel_part = sp_part + 512 * H;        // 512*768
  float* sp_cnt   = sel_part + 512 * H;       // 512
  float* sel_cnt  = sp_cnt + 512;             // 512
  float* sp       = sel_cnt + 512;            // 16*768
  float* sel_ln   = sp + B * H;               // 16*768
  float* q        = sel_ln + B * H;           // 16*768
  float* pooled   = q + B * H;                // 16*8*768
  float* yb       = pooled + B * NS * H;      // 16*8*768
  float* cls_out  = yb + B * NS * H;          // 16*8*768

  k_row_cls<<<512, 192, 0, stream>>>(expl_h1, expl_h2, extra_am, row_cls);
  k_sent_partial<<<B * NCHUNK, 192, 0, stream>>>(sent_h1, sent_h2, attention_mask,
                                                 sp_part, sp_cnt);
  k_sel_partial<<<B * NCHUNK, 192, 0, stream>>>(hidden_states, extra_start, extra_end,
                                                sel_part, sel_cnt);
  k_finalize<<<B, 256, 0, stream>>>(sp_part, sp_cnt, sel_part, sel_cnt, W_attn,
                                    gamma_s, beta_s, sp, sel_ln, q);
  k_attn_pool<<<B * NS, 256, 0, stream>>>(row_cls, q, extra_index, pooled);
  k_transform<<<B * 12, 256, 0, stream>>>(pooled, W_t, b_t, yb);
  k_ln_rows<<<B * NS, 256, 0, stream>>>(yb, gamma_t, beta_t, cls_out);
  k_score<<<B, 256, 0, stream>>>(cls_out, sel_ln, out);
}

// Round 2
// 114.683 us; speedup vs baseline: 1.4020x; 1.4020x over previous
//
#include <hip/hip_runtime.h>
#include <math.h>

// Problem constants (fixed by setup_inputs)
#define B   16
#define L   512
#define H   768
#define HV4 192      // H/4 float4s per row
#define S1  32
#define S2  128
#define NS  8
#define M   4
#define CH  16       // L-chunk rows per partial block
#define NCHUNK 32    // L / CH

// ---------------------------------------------------------------------------
// K1 (fused): 1536 blocks, 192 threads.
//   bid <  512 : row_cls masked mean over expl_h1+expl_h2 (the ~200MB stream)
//   bid < 1024 : sent partial masked sums over 16-row chunks
//   else       : sel span partial sums over 16-row chunks
// Fusing lets the small streams share the launch and the HBM pipe with the
// dominant one instead of serializing behind it.
// ---------------------------------------------------------------------------
__global__ __launch_bounds__(192)
void k_pool(const float* __restrict__ e1, const float* __restrict__ e2,
            const int* __restrict__ am,
            const float* __restrict__ s1, const float* __restrict__ s2,
            const int* __restrict__ iam,
            const float* __restrict__ hs, const int* __restrict__ st_,
            const int* __restrict__ en_,
            float* __restrict__ row_cls,
            float* __restrict__ sp_part, float* __restrict__ sp_cnt,
            float* __restrict__ sel_part, float* __restrict__ sel_cnt) {
  const int bid = blockIdx.x;
  const int t = threadIdx.x;
  if (bid < 512) {
    const int i = bid;
    __shared__ float mk[S2];
    __shared__ int   idxL[S2];
    __shared__ float mvL[S2];
    __shared__ int   cntS;
    __shared__ float msumS;
    if (t < S2) mk[t] = (float)am[i * S2 + t];
    __syncthreads();
    if (t == 0) {
      int c = 0; float s = 0.f;
      for (int j = 0; j < S2; ++j) {
        float m = mk[j]; s += m;
        if (m != 0.f) { idxL[c] = j; mvL[c] = m; ++c; }
      }
      cntS = c; msumS = s;
    }
    __syncthreads();
    const int cnt = cntS;
    const float4* p1 = (const float4*)e1 + (size_t)i * (S2 * HV4);
    const float4* p2 = (const float4*)e2 + (size_t)i * (S2 * HV4);
    float ax = 0.f, ay = 0.f, az = 0.f, aw = 0.f;
    int kk = 0;
    for (; kk + 3 < cnt; kk += 4) {
      int j0 = idxL[kk], j1 = idxL[kk + 1], j2 = idxL[kk + 2], j3 = idxL[kk + 3];
      float m0 = mvL[kk], m1 = mvL[kk + 1], m2 = mvL[kk + 2], m3 = mvL[kk + 3];
      float4 a0 = p1[j0 * HV4 + t], b0 = p2[j0 * HV4 + t];
      float4 a1 = p1[j1 * HV4 + t], b1 = p2[j1 * HV4 + t];
      float4 a2 = p1[j2 * HV4 + t], b2 = p2[j2 * HV4 + t];
      float4 a3 = p1[j3 * HV4 + t], b3 = p2[j3 * HV4 + t];
      ax += m0 * (a0.x + b0.x) + m1 * (a1.x + b1.x) + m2 * (a2.x + b2.x) + m3 * (a3.x + b3.x);
      ay += m0 * (a0.y + b0.y) + m1 * (a1.y + b1.y) + m2 * (a2.y + b2.y) + m3 * (a3.y + b3.y);
      az += m0 * (a0.z + b0.z) + m1 * (a1.z + b1.z) + m2 * (a2.z + b2.z) + m3 * (a3.z + b3.z);
      aw += m0 * (a0.w + b0.w) + m1 * (a1.w + b1.w) + m2 * (a2.w + b2.w) + m3 * (a3.w + b3.w);
    }
    for (; kk < cnt; ++kk) {
      int j = idxL[kk]; float m = mvL[kk];
      float4 a = p1[j * HV4 + t], b = p2[j * HV4 + t];
      ax += m * (a.x + b.x); ay += m * (a.y + b.y);
      az += m * (a.z + b.z); aw += m * (a.w + b.w);
    }
    float inv = 1.f / msumS;
    float4 o; o.x = ax * inv; o.y = ay * inv; o.z = az * inv; o.w = aw * inv;
    ((float4*)row_cls)[(size_t)i * HV4 + t] = o;
  } else if (bid < 1024) {
    const int blk = bid - 512;
    const int b = blk >> 5, c = blk & 31;
    __shared__ float mk2[CH];
    __shared__ int   idx2[CH];
    __shared__ float mv2[CH];
    __shared__ int   cnt2;
    if (t < CH) mk2[t] = (float)iam[b * L + c * CH + t];
    __syncthreads();
    if (t == 0) {
      int cc = 0; float s = 0.f;
      for (int l = 0; l < CH; ++l) {
        float m = mk2[l]; s += m;
        if (m != 0.f) { idx2[cc] = l; mv2[cc] = m; ++cc; }
      }
      cnt2 = cc; sp_cnt[blk] = s;
    }
    __syncthreads();
    const int cn = cnt2;
    const float4* p1 = (const float4*)s1 + ((size_t)b * L + c * CH) * HV4;
    const float4* p2 = (const float4*)s2 + ((size_t)b * L + c * CH) * HV4;
    float ax = 0.f, ay = 0.f, az = 0.f, aw = 0.f;
    int kk = 0;
    for (; kk + 1 < cn; kk += 2) {
      int l0 = idx2[kk], l1 = idx2[kk + 1];
      float m0 = mv2[kk], m1 = mv2[kk + 1];
      float4 a0 = p1[l0 * HV4 + t], b0 = p2[l0 * HV4 + t];
      float4 a1 = p1[l1 * HV4 + t], b1 = p2[l1 * HV4 + t];
      ax += m0 * (a0.x + b0.x) + m1 * (a1.x + b1.x);
      ay += m0 * (a0.y + b0.y) + m1 * (a1.y + b1.y);
      az += m0 * (a0.z + b0.z) + m1 * (a1.z + b1.z);
      aw += m0 * (a0.w + b0.w) + m1 * (a1.w + b1.w);
    }
    for (; kk < cn; ++kk) {
      int l = idx2[kk]; float m = mv2[kk];
      float4 a = p1[l * HV4 + t], b = p2[l * HV4 + t];
      ax += m * (a.x + b.x); ay += m * (a.y + b.y);
      az += m * (a.z + b.z); aw += m * (a.w + b.w);
    }
    float4 o; o.x = ax; o.y = ay; o.z = az; o.w = aw;
    ((float4*)sp_part)[(size_t)blk * HV4 + t] = o;
  } else {
    const int blk = bid - 1024;
    const int b = blk >> 5, c = blk & 31;
    const int st = st_[b], en = en_[b];
    int lo = st > c * CH ? st : c * CH;
    int hi = en < c * CH + CH ? en : c * CH + CH;
    const float4* p = (const float4*)hs + (size_t)b * L * HV4;
    float ax = 0.f, ay = 0.f, az = 0.f, aw = 0.f;
    int l = lo;
    for (; l + 1 < hi; l += 2) {
      float4 a0 = p[l * HV4 + t];
      float4 a1 = p[(l + 1) * HV4 + t];
      ax += a0.x + a1.x; ay += a0.y + a1.y; az += a0.z + a1.z; aw += a0.w + a1.w;
    }
    if (l < hi) {
      float4 a0 = p[l * HV4 + t];
      ax += a0.x; ay += a0.y; az += a0.z; aw += a0.w;
    }
    float4 o; o.x = ax; o.y = ay; o.z = az; o.w = aw;
    ((float4*)sel_part)[(size_t)blk * HV4 + t] = o;
    if (t == 0) sel_cnt[blk] = (float)(hi > lo ? hi - lo : 0);
  }
}

// ---------------------------------------------------------------------------
// K2 (fused): grid 16 + 192 = 208 blocks, 256 threads.
//   bid < 16 : combine sel partials + LayerNorm(gamma_s/beta_s) -> sel_ln
//   else     : q[b, 64-h tile] = sp[b,:] @ W_attn, d split 4-way per block.
//              Each q block re-derives sp[b,:] from sp_part (96KB L2, cheap),
//              trading that for 12x more parallelism on the W_attn read.
// ---------------------------------------------------------------------------
__global__ __launch_bounds__(256)
void k_mid(const float* __restrict__ sp_part, const float* __restrict__ sp_cnt,
           const float* __restrict__ sel_part, const float* __restrict__ sel_cnt,
           const float* __restrict__ W_attn,
           const float* __restrict__ gamma_s, const float* __restrict__ beta_s,
           float* __restrict__ sel_ln, float* __restrict__ q) {
  __shared__ float spL[H];
  __shared__ float red[256];
  __shared__ float mv[2];
  const int bid = blockIdx.x, t = threadIdx.x;
  if (bid < B) {
    const int b = bid;
    float csel = 0.f;
    for (int c = 0; c < NCHUNK; ++c) csel += sel_cnt[b * NCHUNK + c];
    float selv[3];
    #pragma unroll
    for (int k = 0; k < 3; ++k) {
      const int h = t + k * 256;
      float s = 0.f;
      for (int c = 0; c < NCHUNK; ++c)
        s += sel_part[((size_t)b * NCHUNK + c) * H + h];
      selv[k] = s / csel;
    }
    red[t] = selv[0] + selv[1] + selv[2];
    __syncthreads();
    for (int s = 128; s > 0; s >>= 1) { if (t < s) red[t] += red[t + s]; __syncthreads(); }
    if (t == 0) mv[0] = red[0] / (float)H;
    __syncthreads();
    const float mu = mv[0];
    float lv = 0.f;
    #pragma unroll
    for (int k = 0; k < 3; ++k) { float d = selv[k] - mu; lv += d * d; }
    red[t] = lv;
    __syncthreads();
    for (int s = 128; s > 0; s >>= 1) { if (t < s) red[t] += red[t + s]; __syncthreads(); }
    if (t == 0) mv[1] = red[0] / (float)H;
    __syncthreads();
    const float rstd = rsqrtf(mv[1] + 1e-12f);
    #pragma unroll
    for (int k = 0; k < 3; ++k) {
      const int h = t + k * 256;
      sel_ln[(size_t)b * H + h] = (selv[k] - mu) * rstd * gamma_s[h] + beta_s[h];
    }
  } else {
    const int qb = bid - B;             // 0..191
    const int b = qb / 12, ht = qb % 12;
    float csp = 0.f;
    for (int c = 0; c < NCHUNK; ++c) csp += sp_cnt[b * NCHUNK + c];
    const float inv = 1.f / csp;
    #pragma unroll
    for (int k = 0; k < 3; ++k) {
      const int h = t + k * 256;
      float a = 0.f;
      for (int c = 0; c < NCHUNK; ++c)
        a += sp_part[((size_t)b * NCHUNK + c) * H + h];
      spL[h] = a * inv;
    }
    __syncthreads();
    const int hl = t & 63, dseg = t >> 6;
    const int h = ht * 64 + hl;
    const float* wp = W_attn + (size_t)(dseg * 192) * H + h;
    const float* sv = spL + dseg * 192;
    float acc = 0.f;
    #pragma unroll 4
    for (int i = 0; i < 192; ++i) acc += sv[i] * wp[(size_t)i * H];
    red[t] = acc;
    __syncthreads();
    if (t < 64)
      q[(size_t)b * H + ht * 64 + t] = red[t] + red[t + 64] + red[t + 128] + red[t + 192];
  }
}

// ---------------------------------------------------------------------------
// K3: sim -> ragged softmax -> pooled.  Grid: B*NS = 128 blocks, 256 threads.
// ---------------------------------------------------------------------------
__global__ __launch_bounds__(256)
void k_attn_pool(const float* __restrict__ row_cls, const float* __restrict__ q,
                 const int* __restrict__ extra_index, float* __restrict__ pooled) {
  const int blk = blockIdx.x;
  const int b = blk >> 3, n = blk & 7;
  const int t = threadIdx.x;
  const size_t base = ((size_t)b * S1 + n * M) * H;
  __shared__ float red[256];
  __shared__ float wgt[M];
  float qv[3];
  #pragma unroll
  for (int k = 0; k < 3; ++k) qv[k] = q[(size_t)b * H + t + k * 256];
  #pragma unroll
  for (int m = 0; m < M; ++m) {
    float p = 0.f;
    #pragma unroll
    for (int k = 0; k < 3; ++k) {
      const int h = t + k * 256;
      p += qv[k] * row_cls[base + (size_t)m * H + h];
    }
    red[t] = p;
    __syncthreads();
    for (int s = 128; s > 0; s >>= 1) { if (t < s) red[t] += red[t + s]; __syncthreads(); }
    if (t == 0) wgt[m] = red[0];
    __syncthreads();
  }
  if (t == 0) {
    const int vid = extra_index[b * NS + n];
    const float scale = 0.036084391824351615f;  // 1/sqrt(768)
    float x[M], mx = -1e30f;
    #pragma unroll
    for (int m = 0; m < M; ++m) {
      x[m] = (m < vid) ? wgt[m] * scale : -1e30f;
      mx = fmaxf(mx, x[m]);
    }
    float s = 0.f, e[M];
    #pragma unroll
    for (int m = 0; m < M; ++m) { e[m] = expf(x[m] - mx); s += e[m]; }
    #pragma unroll
    for (int m = 0; m < M; ++m) wgt[m] = e[m] / s;
  }
  __syncthreads();
  #pragma unroll
  for (int k = 0; k < 3; ++k) {
    const int h = t + k * 256;
    float acc = 0.f;
    #pragma unroll
    for (int m = 0; m < M; ++m) acc += wgt[m] * row_cls[base + (size_t)m * H + h];
    pooled[(size_t)blk * H + h] = acc;
  }
}

// ---------------------------------------------------------------------------
// K4: y[b,n,h] = pooled[b,n,:] . W_t[h,:] + b_t[h]  (float4, shared W load
// between the two n-accumulators).  Grid: B*12, 256 threads.
// ---------------------------------------------------------------------------
__global__ __launch_bounds__(256)
void k_transform(const float* __restrict__ pooled, const float* __restrict__ W_t,
                 const float* __restrict__ b_t, float* __restrict__ y) {
  const int blk = blockIdx.x;
  const int b = blk / 12, hc = blk % 12;
  const int t = threadIdx.x;
  __shared__ float pL[NS * H];  // 24 KiB
  for (int idx = t; idx < NS * H; idx += 256)
    pL[idx] = pooled[(size_t)b * NS * H + idx];
  __syncthreads();
  const int hl = t & 63;
  const int n0 = t >> 6;            // 0..3 (whole wave shares n -> LDS bcast)
  const int h = hc * 64 + hl;
  const float4* wr = (const float4*)(W_t + (size_t)h * H);
  const float4* pr0 = (const float4*)(pL + n0 * H);
  const float4* pr1 = (const float4*)(pL + (n0 + 4) * H);
  float acc0 = 0.f, acc1 = 0.f;
  #pragma unroll 4
  for (int d = 0; d < HV4; ++d) {
    float4 w = wr[d];
    float4 p0 = pr0[d], p1 = pr1[d];
    acc0 += w.x * p0.x + w.y * p0.y + w.z * p0.z + w.w * p0.w;
    acc1 += w.x * p1.x + w.y * p1.y + w.z * p1.z + w.w * p1.w;
  }
  const float bias = b_t[h];
  y[((size_t)b * NS + n0) * H + h] = acc0 + bias;
  y[((size_t)b * NS + n0 + 4) * H + h] = acc1 + bias;
}

// ---------------------------------------------------------------------------
// K5: fused row-LayerNorm + cosine score.  cls_out is never materialized:
// score only needs S = sum_n c and SS = sum_n c^2 per h.  Grid: B blocks.
// ---------------------------------------------------------------------------
__global__ __launch_bounds__(256)
void k_lnscore(const float* __restrict__ y, const float* __restrict__ gamma,
               const float* __restrict__ beta, const float* __restrict__ sel_ln,
               float* __restrict__ out) {
  const int b = blockIdx.x, t = threadIdx.x;
  __shared__ float red[256];
  __shared__ float mv[2];
  float g[3], be[3];
  #pragma unroll
  for (int k = 0; k < 3; ++k) { g[k] = gamma[t + k * 256]; be[k] = beta[t + k * 256]; }
  float S[3] = {0.f, 0.f, 0.f}, SS[3] = {0.f, 0.f, 0.f};
  for (int n = 0; n < NS; ++n) {
    float v[3];
    #pragma unroll
    for (int k = 0; k < 3; ++k) v[k] = y[((size_t)b * NS + n) * H + t + k * 256];
    red[t] = v[0] + v[1] + v[2];
    __syncthreads();
    for (int s = 128; s > 0; s >>= 1) { if (t < s) red[t] += red[t + s]; __syncthreads(); }
    if (t == 0) mv[0] = red[0] / (float)H;
    __syncthreads();
    const float mu = mv[0];
    float lv = 0.f;
    #pragma unroll
    for (int k = 0; k < 3; ++k) { float d = v[k] - mu; lv += d * d; }
    red[t] = lv;
    __syncthreads();
    for (int s = 128; s > 0; s >>= 1) { if (t < s) red[t] += red[t + s]; __syncthreads(); }
    if (t == 0) mv[1] = red[0] / (float)H;
    __syncthreads();
    const float rstd = rsqrtf(mv[1] + 1e-12f);
    #pragma unroll
    for (int k = 0; k < 3; ++k) {
      const float c = (v[k] - mu) * rstd * g[k] + be[k];
      S[k] += c; SS[k] += c * c;
    }
    __syncthreads();
  }
  #pragma unroll
  for (int k = 0; k < 3; ++k) {
    const int h = t + k * 256;
    const float sl = sel_ln[(size_t)b * H + h];
    const float n1 = 2.8284271247461903f * fabsf(sl);  // sqrt(8)*|sel|
    const float n2 = sqrtf(SS[k]);
    out[(size_t)b * H + h] = sl * S[k] / (fmaxf(n1, 1e-8f) * fmaxf(n2, 1e-8f));
  }
}

// ---------------------------------------------------------------------------
extern "C" void kernel_launch(void* const* d_in, const int* in_sizes, int n_in,
                              void* d_out, int out_size, void* d_ws, size_t ws_size,
                              hipStream_t stream) {
  const float* hidden_states = (const float*)d_in[0];
  const float* sent_h1       = (const float*)d_in[1];
  const float* sent_h2       = (const float*)d_in[2];
  const int*   attention_mask= (const int*)  d_in[3];
  const float* expl_h1       = (const float*)d_in[4];
  const float* expl_h2       = (const float*)d_in[5];
  const int*   extra_am      = (const int*)  d_in[6];
  const int*   extra_index   = (const int*)  d_in[7];
  const int*   extra_start   = (const int*)  d_in[8];
  const int*   extra_end     = (const int*)  d_in[9];
  const float* W_attn        = (const float*)d_in[10];
  const float* W_t           = (const float*)d_in[11];
  const float* b_t           = (const float*)d_in[12];
  const float* gamma_t       = (const float*)d_in[13];
  const float* beta_t        = (const float*)d_in[14];
  const float* gamma_s       = (const float*)d_in[15];
  const float* beta_s        = (const float*)d_in[16];
  float* out = (float*)d_out;

  float* ws = (float*)d_ws;
  float* row_cls  = ws;                       // 512*768
  float* sp_part  = row_cls + 512 * H;        // 512*768
  float* sel_part = sp_part + 512 * H;        // 512*768
  float* sp_cnt   = sel_part + 512 * H;       // 512
  float* sel_cnt  = sp_cnt + 512;             // 512
  float* sel_ln   = sel_cnt + 512;            // 16*768
  float* q        = sel_ln + B * H;           // 16*768
  float* pooled   = q + B * H;                // 16*8*768
  float* yb       = pooled + B * NS * H;      // 16*8*768

  k_pool<<<1536, 192, 0, stream>>>(expl_h1, expl_h2, extra_am,
                                   sent_h1, sent_h2, attention_mask,
                                   hidden_states, extra_start, extra_end,
                                   row_cls, sp_part, sp_cnt, sel_part, sel_cnt);
  k_mid<<<B + 192, 256, 0, stream>>>(sp_part, sp_cnt, sel_part, sel_cnt, W_attn,
                                     gamma_s, beta_s, sel_ln, q);
  k_attn_pool<<<B * NS, 256, 0, stream>>>(row_cls, q, extra_index, pooled);
  k_transform<<<B * 12, 256, 0, stream>>>(pooled, W_t, b_t, yb);
  k_lnscore<<<B, 256, 0, stream>>>(yb, gamma_t, beta_t, sel_ln, out);
}